// Round 1
// baseline (284.379 us; speedup 1.0000x reference)
//
#include <hip/hip_runtime.h>
#include <hip/hip_fp16.h>

// TriMipEncoding: N pts, 3 planes (512^2, 16 ch), 8 mip levels, trilinear sample.
//
// Fast path (ws_size >= 33.6 MB): full fp16 pyramid (levels 0..7) in d_ws.
//   Texel = 16 halfs = 32 B. Per-plane texel offset of level l:
//   off(l) = (2^20 - (2^20 >> 2l)) / 3. Plane stride = 349520 texels.
// R3 evidence: sampler duration identical at FETCH=0 vs FETCH=122MB -> NOT
// HBM-bound; bound is divergent-gather request rate on the vmem pipe.
// R4: stage levels 5..7 (31.5 KB, all planes) in LDS -> ~36% of tap
// requests move to the (idle) LDS pipe.
// R5 (this round): lane-address model: 6-threads/point scheme issues ~67
// global lane-addresses/point (31 taps + 24 redundant xyz/level + 12 stores)
// ~= measured 65 us at ~1 addr/cy/CU. Switch to ONE thread per point
// (all 3 planes x 2 levels x 16 ch): 47 addresses/point (0.70x), setup
// VALU deduped 6x. Level-lerp folded into tap accumulation to keep one
// 16-ch accumulator live (~70 VGPR). Plane loop rolled to avoid spills.

typedef float        f4v   __attribute__((ext_vector_type(4)));
typedef unsigned int u32x2 __attribute__((ext_vector_type(2)));
typedef unsigned int u32x4 __attribute__((ext_vector_type(4)));

#define FM_PLANE_STRIDE (262144 * 16)   // floats per plane in fm
#define WS_PLANE_STRIDE (87376 * 16)    // floats per plane, fp32 fallback pyramid
#define PSTRIDE_H (349520 * 16)         // halfs per plane, fp16 full pyramid
#define WS_H_BYTES (3ull * PSTRIDE_H * 2ull)
#define LVL5_OFF 349184u                // texel offset of level 5 (levels 5..7 contiguous)

__device__ __forceinline__ unsigned lvl_off(int l) {   // texel offset of level l
    return (1048576u - (1048576u >> (2 * l))) / 3u;
}

__device__ __forceinline__ f4v ld4(const float* p) {
    return *reinterpret_cast<const f4v*>(p);
}
__device__ __forceinline__ f4v ld4nt(const float* p) {
    return __builtin_nontemporal_load(reinterpret_cast<const f4v*>(p));
}
__device__ __forceinline__ void st4(float* p, f4v v) {
    *reinterpret_cast<f4v*>(p) = v;
}
__device__ __forceinline__ void st4nt(float* p, f4v v) {
    __builtin_nontemporal_store(v, reinterpret_cast<f4v*>(p));
}
__device__ __forceinline__ f4v ldraw_h(const __half* p) {   // 8 halfs as raw f4v
    return *reinterpret_cast<const f4v*>(p);
}
__device__ __forceinline__ u32x2 pack4(f4v v) {             // 4 floats -> 4 halfs
    __half2 lo = __floats2half2_rn(v.x, v.y);
    __half2 hi = __floats2half2_rn(v.z, v.w);
    u32x2 r;
    r.x = *reinterpret_cast<unsigned*>(&lo);
    r.y = *reinterpret_cast<unsigned*>(&hi);
    return r;
}
__device__ __forceinline__ f4v h4f(const __half* p) {       // 4 halfs -> 4 floats
    u32x2 u = *reinterpret_cast<const u32x2*>(p);
    unsigned a0 = u.x, a1 = u.y;
    __half2 lo = *reinterpret_cast<__half2*>(&a0);
    __half2 hi = *reinterpret_cast<__half2*>(&a1);
    float2 flo = __half22float2(lo), fhi = __half22float2(hi);
    f4v r; r.x = flo.x; r.y = flo.y; r.z = fhi.x; r.w = fhi.y;
    return r;
}
__device__ __forceinline__ float2 up2(float rawcomp) {      // 2 packed halfs -> 2 floats
    unsigned u = __float_as_uint(rawcomp);
    __half2 hh = *reinterpret_cast<__half2*>(&u);
    return __half22float2(hh);
}

// ---------------- fp16 path ----------------

// fm (fp32) -> L0' (fp16) + L1 (fp16). Thread per (L1 texel, quad q); grid (1024, 3).
__global__ __launch_bounds__(256) void mip_convert_l1(
    const float* __restrict__ fm, __half* __restrict__ wsh)
{
    int t = blockIdx.x * 256 + threadIdx.x;
    const int p = blockIdx.y;
    const int q = t & 3, idx = t >> 2;
    const int y = idx >> 8, x = idx & 255;
    const float* sp = fm + (size_t)p * FM_PLANE_STRIDE
                         + ((size_t)(2 * y) * 512 + 2 * x) * 16 + q * 4;
    f4v a = ld4nt(sp);
    f4v b = ld4nt(sp + 16);
    f4v c = ld4nt(sp + 512 * 16);
    f4v d = ld4nt(sp + 512 * 16 + 16);
    __half* L0 = wsh + (size_t)p * PSTRIDE_H;
    size_t o00 = ((size_t)(2 * y) * 512 + 2 * x) * 16 + q * 4;
    *reinterpret_cast<u32x2*>(L0 + o00)                 = pack4(a);
    *reinterpret_cast<u32x2*>(L0 + o00 + 16)            = pack4(b);
    *reinterpret_cast<u32x2*>(L0 + o00 + 512 * 16)      = pack4(c);
    *reinterpret_cast<u32x2*>(L0 + o00 + 512 * 16 + 16) = pack4(d);
    f4v m = (a + b + c + d) * 0.25f;   // L1 from fp32 source, single rounding
    __half* L1 = wsh + (size_t)p * PSTRIDE_H + (size_t)262144 * 16;
    *reinterpret_cast<u32x2*>(L1 + ((size_t)y * 256 + x) * 16 + q * 4) = pack4(m);
}

// Fused L2..L7 (fp16). Block = (32x32 L2 tile, quad q, plane p); grid (16,4,3).
__global__ __launch_bounds__(256) void mip_tail_h(__half* __restrict__ wsh)
{
    const int tile = blockIdx.x;
    const int q    = blockIdx.y;
    const int p    = blockIdx.z;
    const int ty = tile >> 2, tx = tile & 3;
    const int tid = threadIdx.x;

    __shared__ f4v A[32 * 32];
    __shared__ f4v B[16 * 16];

    __half* plane = wsh + (size_t)p * PSTRIDE_H;
    const __half* L1 = plane + (size_t)lvl_off(1) * 16;
    __half* L2 = plane + (size_t)lvl_off(2) * 16;
    __half* L3 = plane + (size_t)lvl_off(3) * 16;
    __half* L4 = plane + (size_t)lvl_off(4) * 16;
    __half* L5 = plane + (size_t)lvl_off(5) * 16;
    __half* L6 = plane + (size_t)lvl_off(6) * 16;
    __half* L7 = plane + (size_t)lvl_off(7) * 16;

    #pragma unroll
    for (int k = 0; k < 4; ++k) {
        int li = tid + k * 256;
        int ly = li >> 5, lx = li & 31;
        int gy = ty * 32 + ly, gx = tx * 32 + lx;
        const __half* sp = L1 + ((size_t)(2 * gy) * 256 + 2 * gx) * 16 + q * 4;
        f4v r = (h4f(sp) + h4f(sp + 16) + h4f(sp + 256 * 16) + h4f(sp + 256 * 16 + 16)) * 0.25f;
        A[li] = r;
        *reinterpret_cast<u32x2*>(L2 + ((size_t)gy * 128 + gx) * 16 + q * 4) = pack4(r);
    }
    __syncthreads();

    {   // L3: 16x16
        int ly = tid >> 4, lx = tid & 15;
        f4v r = (A[(2 * ly) * 32 + 2 * lx]     + A[(2 * ly) * 32 + 2 * lx + 1] +
                 A[(2 * ly + 1) * 32 + 2 * lx] + A[(2 * ly + 1) * 32 + 2 * lx + 1]) * 0.25f;
        B[tid] = r;
        *reinterpret_cast<u32x2*>(L3 + ((size_t)(ty * 16 + ly) * 64 + tx * 16 + lx) * 16 + q * 4) = pack4(r);
    }
    __syncthreads();

    if (tid < 64) {   // L4: 8x8
        int ly = tid >> 3, lx = tid & 7;
        f4v r = (B[(2 * ly) * 16 + 2 * lx]     + B[(2 * ly) * 16 + 2 * lx + 1] +
                 B[(2 * ly + 1) * 16 + 2 * lx] + B[(2 * ly + 1) * 16 + 2 * lx + 1]) * 0.25f;
        A[tid] = r;
        *reinterpret_cast<u32x2*>(L4 + ((size_t)(ty * 8 + ly) * 32 + tx * 8 + lx) * 16 + q * 4) = pack4(r);
    }
    __syncthreads();

    if (tid < 16) {   // L5: 4x4
        int ly = tid >> 2, lx = tid & 3;
        f4v r = (A[(2 * ly) * 8 + 2 * lx]     + A[(2 * ly) * 8 + 2 * lx + 1] +
                 A[(2 * ly + 1) * 8 + 2 * lx] + A[(2 * ly + 1) * 8 + 2 * lx + 1]) * 0.25f;
        B[tid] = r;
        *reinterpret_cast<u32x2*>(L5 + ((size_t)(ty * 4 + ly) * 16 + tx * 4 + lx) * 16 + q * 4) = pack4(r);
    }
    __syncthreads();

    if (tid < 4) {    // L6: 2x2
        int ly = tid >> 1, lx = tid & 1;
        f4v r = (B[(2 * ly) * 4 + 2 * lx]     + B[(2 * ly) * 4 + 2 * lx + 1] +
                 B[(2 * ly + 1) * 4 + 2 * lx] + B[(2 * ly + 1) * 4 + 2 * lx + 1]) * 0.25f;
        A[tid] = r;
        *reinterpret_cast<u32x2*>(L6 + ((size_t)(ty * 2 + ly) * 8 + tx * 2 + lx) * 16 + q * 4) = pack4(r);
    }
    __syncthreads();

    if (tid == 0) {   // L7: 1 texel
        f4v r = (A[0] + A[1] + A[2] + A[3]) * 0.25f;
        *reinterpret_cast<u32x2*>(L7 + ((size_t)ty * 4 + tx) * 16 + q * 4) = pack4(r);
    }
}

// Full-16-channel weighted bilinear tap, accumulating acc += wl * bilerp(l, u, v).
// Levels >= 5 read from the LDS copy. acc = 4x f4v (channels 0..15).
__device__ __forceinline__ void bilerp16_acc(
    const __half* __restrict__ wsh, const __half* __restrict__ lds_h,
    int p, int l, float u, float v, float wl, f4v* acc)
{
    const int sz = 512 >> l;
    const float fsz = (float)sz;
    float px = u * fsz - 0.5f;
    float py = v * fsz - 0.5f;
    float xf = floorf(px), yf = floorf(py);
    float fx = px - xf, fy = py - yf;
    int xi = (int)xf, yi = (int)yf;
    int xa = min(max(xi, 0), sz - 1);
    int xb = min(xi + 1, sz - 1);      // xi >= -1 always
    int ya = min(max(yi, 0), sz - 1);
    int yb = min(yi + 1, sz - 1);
    f4v q00a, q00b, q01a, q01b, q10a, q10b, q11a, q11b;
    if (l >= 5) {
        const int sel = (l == 6) ? 256 : ((l == 7) ? 320 : 0);
        const __half* base = lds_h + (size_t)(p * 336 + sel) * 16;
        const __half* r0 = base + (ya * sz) * 16;
        const __half* r1 = base + (yb * sz) * 16;
        q00a = ldraw_h(r0 + xa * 16); q00b = ldraw_h(r0 + xa * 16 + 8);
        q01a = ldraw_h(r0 + xb * 16); q01b = ldraw_h(r0 + xb * 16 + 8);
        q10a = ldraw_h(r1 + xa * 16); q10b = ldraw_h(r1 + xa * 16 + 8);
        q11a = ldraw_h(r1 + xb * 16); q11b = ldraw_h(r1 + xb * 16 + 8);
    } else {
        const __half* base = wsh + (size_t)p * PSTRIDE_H + (size_t)lvl_off(l) * 16;
        const __half* r0 = base + (size_t)(ya * sz) * 16;
        const __half* r1 = base + (size_t)(yb * sz) * 16;
        q00a = ldraw_h(r0 + (size_t)xa * 16); q00b = ldraw_h(r0 + (size_t)xa * 16 + 8);
        q01a = ldraw_h(r0 + (size_t)xb * 16); q01b = ldraw_h(r0 + (size_t)xb * 16 + 8);
        q10a = ldraw_h(r1 + (size_t)xa * 16); q10b = ldraw_h(r1 + (size_t)xa * 16 + 8);
        q11a = ldraw_h(r1 + (size_t)xb * 16); q11b = ldraw_h(r1 + (size_t)xb * 16 + 8);
    }
    float gx = 1.f - fx, gy = 1.f - fy;
    float w00 = gx * gy * wl, w01 = fx * gy * wl;
    float w10 = gx * fy * wl, w11 = fx * fy * wl;
    #pragma unroll
    for (int i = 0; i < 4; ++i) {
        // channels 2i, 2i+1 (low half of texel)
        float2 a = up2(q00a[i]), b = up2(q01a[i]), c = up2(q10a[i]), d = up2(q11a[i]);
        acc[i >> 1][(i & 1) * 2]     += a.x * w00 + b.x * w01 + c.x * w10 + d.x * w11;
        acc[i >> 1][(i & 1) * 2 + 1] += a.y * w00 + b.y * w01 + c.y * w10 + d.y * w11;
        // channels 8+2i, 8+2i+1 (high half of texel)
        float2 e = up2(q00b[i]), f2 = up2(q01b[i]), g2 = up2(q10b[i]), h2 = up2(q11b[i]);
        acc[2 + (i >> 1)][(i & 1) * 2]     += e.x * w00 + f2.x * w01 + g2.x * w10 + h2.x * w11;
        acc[2 + (i >> 1)][(i & 1) * 2 + 1] += e.y * w00 + f2.y * w01 + g2.y * w10 + h2.y * w11;
    }
}

// One thread per point: all 3 planes x 2 levels x 16 channels.
// Block 512; LDS holds levels 5..7 of all 3 planes (31.5 KB).
__global__ __launch_bounds__(512) void trimip_sample_h(
    const float* __restrict__ xyz, const float* __restrict__ level,
    const __half* __restrict__ wsh, float* __restrict__ out, int N)
{
    __shared__ u32x4 lds[2016];       // 3 planes * 336 texels * 32 B = 32256 B
    for (int uidx = threadIdx.x; uidx < 2016; uidx += 512) {
        int p = uidx / 672;           // 672 16-B units per plane
        int rem = uidx - p * 672;
        lds[uidx] = *reinterpret_cast<const u32x4*>(
            wsh + (size_t)p * PSTRIDE_H + (size_t)LVL5_OFF * 16 + (size_t)rem * 8);
    }
    __syncthreads();
    const __half* lds_h = reinterpret_cast<const __half*>(lds);

    int n = blockIdx.x * 512 + threadIdx.x;
    if (n >= N) return;

    const float c0 = xyz[n * 3 + 0];
    const float c1 = xyz[n * 3 + 1];
    const float c2 = xyz[n * 3 + 2];

    float lv = level[n];
    lv = fminf(fmaxf(lv, 0.f), 7.f);
    float lf = floorf(lv);
    float f = lv - lf;
    int l0 = (int)lf;
    int l1 = min(l0 + 1, 7);
    float g = 1.f - f;

    float* op = out + (size_t)n * 48;
    #pragma unroll 1                  // rolled: controls VGPR (taps+acc ~70 regs)
    for (int p = 0; p < 3; ++p) {
        const float u = (p == 0) ? c1 : c0;
        const float v = (p == 2) ? c1 : c2;
        f4v acc[4];
        #pragma unroll
        for (int j = 0; j < 4; ++j) acc[j] = (f4v)0.f;
        bilerp16_acc(wsh, lds_h, p, l0, u, v, g, acc);
        bilerp16_acc(wsh, lds_h, p, l1, u, v, f, acc);
        st4nt(op + p * 16 + 0,  acc[0]);
        st4nt(op + p * 16 + 4,  acc[1]);
        st4nt(op + p * 16 + 8,  acc[2]);
        st4nt(op + p * 16 + 12, acc[3]);
    }
}

// ---------------- fp32 fallback path ----------------

__device__ __forceinline__ f4v avg4(f4v a, f4v b, f4v c, f4v d) {
    return (a + b + c + d) * 0.25f;
}

__global__ __launch_bounds__(256) void mip_build_f(
    const float* __restrict__ src, float* __restrict__ dst)
{
    int t = blockIdx.x * blockDim.x + threadIdx.x;
    const int p = blockIdx.y;
    const int q = t & 3, idx = t >> 2;
    const int y = idx >> 8, x = idx & 255;
    const float* sp = src + (size_t)p * FM_PLANE_STRIDE
                          + ((size_t)(2 * y) * 512 + 2 * x) * 16 + q * 4;
    f4v r = avg4(ld4(sp), ld4(sp + 16), ld4(sp + 512 * 16), ld4(sp + 512 * 16 + 16));
    st4(dst + (size_t)p * WS_PLANE_STRIDE + ((size_t)y * 256 + x) * 16 + q * 4, r);
}

__global__ __launch_bounds__(256) void mip_tail_f(float* __restrict__ mips)
{
    const int tile = blockIdx.x, q = blockIdx.y, p = blockIdx.z;
    const int ty = tile >> 2, tx = tile & 3;
    const int tid = threadIdx.x;
    __shared__ f4v A[32 * 32];
    __shared__ f4v B[16 * 16];
    float* plane = mips + (size_t)p * WS_PLANE_STRIDE;
    const float* L1 = plane;
    float* L2 = plane + (size_t)65536 * 16;
    float* L3 = plane + (size_t)81920 * 16;
    float* L4 = plane + (size_t)86016 * 16;
    float* L5 = plane + (size_t)87040 * 16;
    float* L6 = plane + (size_t)87296 * 16;
    float* L7 = plane + (size_t)87360 * 16;

    #pragma unroll
    for (int k = 0; k < 4; ++k) {
        int li = tid + k * 256;
        int ly = li >> 5, lx = li & 31;
        int gy = ty * 32 + ly, gx = tx * 32 + lx;
        const float* sp = L1 + ((size_t)(2 * gy) * 256 + 2 * gx) * 16 + q * 4;
        f4v r = avg4(ld4(sp), ld4(sp + 16), ld4(sp + 256 * 16), ld4(sp + 256 * 16 + 16));
        A[li] = r;
        st4(L2 + ((size_t)gy * 128 + gx) * 16 + q * 4, r);
    }
    __syncthreads();
    {
        int ly = tid >> 4, lx = tid & 15;
        f4v r = avg4(A[(2 * ly) * 32 + 2 * lx],     A[(2 * ly) * 32 + 2 * lx + 1],
                     A[(2 * ly + 1) * 32 + 2 * lx], A[(2 * ly + 1) * 32 + 2 * lx + 1]);
        B[tid] = r;
        st4(L3 + ((size_t)(ty * 16 + ly) * 64 + tx * 16 + lx) * 16 + q * 4, r);
    }
    __syncthreads();
    if (tid < 64) {
        int ly = tid >> 3, lx = tid & 7;
        f4v r = avg4(B[(2 * ly) * 16 + 2 * lx],     B[(2 * ly) * 16 + 2 * lx + 1],
                     B[(2 * ly + 1) * 16 + 2 * lx], B[(2 * ly + 1) * 16 + 2 * lx + 1]);
        A[tid] = r;
        st4(L4 + ((size_t)(ty * 8 + ly) * 32 + tx * 8 + lx) * 16 + q * 4, r);
    }
    __syncthreads();
    if (tid < 16) {
        int ly = tid >> 2, lx = tid & 3;
        f4v r = avg4(A[(2 * ly) * 8 + 2 * lx],     A[(2 * ly) * 8 + 2 * lx + 1],
                     A[(2 * ly + 1) * 8 + 2 * lx], A[(2 * ly + 1) * 8 + 2 * lx + 1]);
        B[tid] = r;
        st4(L5 + ((size_t)(ty * 4 + ly) * 16 + tx * 4 + lx) * 16 + q * 4, r);
    }
    __syncthreads();
    if (tid < 4) {
        int ly = tid >> 1, lx = tid & 1;
        f4v r = avg4(B[(2 * ly) * 4 + 2 * lx],     B[(2 * ly) * 4 + 2 * lx + 1],
                     B[(2 * ly + 1) * 4 + 2 * lx], B[(2 * ly + 1) * 4 + 2 * lx + 1]);
        A[tid] = r;
        st4(L6 + ((size_t)(ty * 2 + ly) * 8 + tx * 2 + lx) * 16 + q * 4, r);
    }
    __syncthreads();
    if (tid == 0) {
        f4v r = avg4(A[0], A[1], A[2], A[3]);
        st4(L7 + ((size_t)ty * 4 + tx) * 16 + q * 4, r);
    }
}

__device__ __forceinline__ f4v bilerp_f(
    const float* __restrict__ fm, const float* __restrict__ mips,
    int p, int l, float u, float v, int q)
{
    const int sz = 512 >> l;
    const float fsz = (float)sz;
    float px = u * fsz - 0.5f;
    float py = v * fsz - 0.5f;
    float xf = floorf(px), yf = floorf(py);
    float fx = px - xf, fy = py - yf;
    int xi = (int)xf, yi = (int)yf;
    int xa = min(max(xi, 0), sz - 1);
    int xb = min(xi + 1, sz - 1);
    int ya = min(max(yi, 0), sz - 1);
    int yb = min(yi + 1, sz - 1);
    const float* base;
    if (l == 0) {
        base = fm + (size_t)p * FM_PLANE_STRIDE;
    } else {
        unsigned off = (262144u - ((unsigned)(sz * sz) << 2)) / 3u;
        base = mips + (size_t)p * WS_PLANE_STRIDE + (size_t)off * 16;
    }
    const float* r0 = base + (size_t)(ya * sz) * 16 + q * 4;
    const float* r1 = base + (size_t)(yb * sz) * 16 + q * 4;
    f4v f00 = ld4(r0 + xa * 16);
    f4v f01 = ld4(r0 + xb * 16);
    f4v f10 = ld4(r1 + xa * 16);
    f4v f11 = ld4(r1 + xb * 16);
    float gx = 1.f - fx, gy = 1.f - fy;
    return (f00 * gx + f01 * fx) * gy + (f10 * gx + f11 * fx) * fy;
}

__global__ __launch_bounds__(256) void trimip_sample_f(
    const float* __restrict__ xyz, const float* __restrict__ level,
    const float* __restrict__ fm, const float* __restrict__ mips,
    float* __restrict__ out, int N)
{
    int t = blockIdx.x * blockDim.x + threadIdx.x;
    if (t >= N * 12) return;
    const int q = t & 3;
    const int r = t >> 2;
    const int n = r / 3;
    const int p = r - n * 3;
    const float c0 = xyz[n * 3 + 0];
    const float c1 = xyz[n * 3 + 1];
    const float c2 = xyz[n * 3 + 2];
    const float u = (p == 0) ? c1 : c0;
    const float v = (p == 2) ? c1 : c2;
    float lv = level[n];
    lv = fminf(fmaxf(lv, 0.f), 7.f);
    float lf = floorf(lv);
    float f = lv - lf;
    int l0 = (int)lf;
    int l1 = min(l0 + 1, 7);
    f4v s0 = bilerp_f(fm, mips, p, l0, u, v, q);
    f4v s1 = bilerp_f(fm, mips, p, l1, u, v, q);
    f4v o = s0 * (1.f - f) + s1 * f;
    st4nt(out + (size_t)t * 4, o);
}

extern "C" void kernel_launch(void* const* d_in, const int* in_sizes, int n_in,
                              void* d_out, int out_size, void* d_ws, size_t ws_size,
                              hipStream_t stream) {
    const float* xyz   = (const float*)d_in[0];
    const float* level = (const float*)d_in[1];
    const float* fm    = (const float*)d_in[2];
    float* out = (float*)d_out;
    const int N = in_sizes[1];

    if (ws_size >= WS_H_BYTES) {
        __half* wsh = (__half*)d_ws;
        mip_convert_l1<<<dim3(1024, 3), dim3(256), 0, stream>>>(fm, wsh);
        mip_tail_h<<<dim3(16, 4, 3), dim3(256), 0, stream>>>(wsh);
        trimip_sample_h<<<(N + 511) / 512, 512, 0, stream>>>(xyz, level, wsh, out, N);
    } else {
        float* mips = (float*)d_ws;
        mip_build_f<<<dim3(1024, 3), dim3(256), 0, stream>>>(fm, mips);
        mip_tail_f<<<dim3(16, 4, 3), dim3(256), 0, stream>>>(mips);
        const int total = N * 12;
        trimip_sample_f<<<(total + 255) / 256, 256, 0, stream>>>(xyz, level, fm, mips, out, N);
    }
}

// Round 2
// 203.490 us; speedup vs baseline: 1.3975x; 1.3975x over previous
//
#include <hip/hip_runtime.h>
#include <hip/hip_fp16.h>

// TriMipEncoding: N pts, 3 planes (512^2, 16 ch), 8 mip levels, trilinear sample.
//
// Fast path (ws_size >= 33.6 MB): full fp16 pyramid (levels 0..7) in d_ws.
//   Texel = 16 halfs = 32 B. Per-plane texel offset of level l:
//   off(l) = (2^20 - (2^20 >> 2l)) / 3. Plane stride = 349520 texels.
// R3 evidence: sampler duration identical at FETCH=0 vs FETCH=122MB -> NOT
// HBM-bound; bound is divergent-gather request rate on the vmem pipe.
// R4: stage levels 5..7 (31.5 KB, all planes) in LDS -> ~36% of tap
// requests move to the (idle) LDS pipe. Block=512: 4 blocks/CU.
// R5 FAILED (one thread per point): WRITE 106->195 MB (192 B/lane stores
// amplify partial lines), occupancy 71->33%, sampler 65->148 us. Lesson:
// the lane-address model only holds with coalescing fixed; the 6-thread
// layout's wave-contiguous stores are load-bearing.
// R6 (this round): keep 6-thread layout; remove the 6x-duplicated
// xyz/level scalar loads (24 of ~67 global lane-addresses/point) by
// cooperatively staging each block's <=87 points into LDS (~4 addr/pt).
// Taps/stores byte-identical to R4. LDS 32256 -> 33664 B, still 4 blk/CU.

typedef float        f4v   __attribute__((ext_vector_type(4)));
typedef unsigned int u32x2 __attribute__((ext_vector_type(2)));
typedef unsigned int u32x4 __attribute__((ext_vector_type(4)));

#define FM_PLANE_STRIDE (262144 * 16)   // floats per plane in fm
#define WS_PLANE_STRIDE (87376 * 16)    // floats per plane, fp32 fallback pyramid
#define PSTRIDE_H (349520 * 16)         // halfs per plane, fp16 full pyramid
#define WS_H_BYTES (3ull * PSTRIDE_H * 2ull)
#define LVL5_OFF 349184u                // texel offset of level 5 (levels 5..7 contiguous)

__device__ __forceinline__ unsigned lvl_off(int l) {   // texel offset of level l
    return (1048576u - (1048576u >> (2 * l))) / 3u;
}

__device__ __forceinline__ f4v ld4(const float* p) {
    return *reinterpret_cast<const f4v*>(p);
}
__device__ __forceinline__ f4v ld4nt(const float* p) {
    return __builtin_nontemporal_load(reinterpret_cast<const f4v*>(p));
}
__device__ __forceinline__ void st4(float* p, f4v v) {
    *reinterpret_cast<f4v*>(p) = v;
}
__device__ __forceinline__ void st4nt(float* p, f4v v) {
    __builtin_nontemporal_store(v, reinterpret_cast<f4v*>(p));
}
__device__ __forceinline__ f4v ldraw_h(const __half* p) {   // 8 halfs as raw f4v
    return *reinterpret_cast<const f4v*>(p);
}
__device__ __forceinline__ u32x2 pack4(f4v v) {             // 4 floats -> 4 halfs
    __half2 lo = __floats2half2_rn(v.x, v.y);
    __half2 hi = __floats2half2_rn(v.z, v.w);
    u32x2 r;
    r.x = *reinterpret_cast<unsigned*>(&lo);
    r.y = *reinterpret_cast<unsigned*>(&hi);
    return r;
}
__device__ __forceinline__ f4v h4f(const __half* p) {       // 4 halfs -> 4 floats
    u32x2 u = *reinterpret_cast<const u32x2*>(p);
    unsigned a0 = u.x, a1 = u.y;
    __half2 lo = *reinterpret_cast<__half2*>(&a0);
    __half2 hi = *reinterpret_cast<__half2*>(&a1);
    float2 flo = __half22float2(lo), fhi = __half22float2(hi);
    f4v r; r.x = flo.x; r.y = flo.y; r.z = fhi.x; r.w = fhi.y;
    return r;
}
__device__ __forceinline__ float2 up2(float rawcomp) {      // 2 packed halfs -> 2 floats
    unsigned u = __float_as_uint(rawcomp);
    __half2 hh = *reinterpret_cast<__half2*>(&u);
    return __half22float2(hh);
}

// ---------------- fp16 path ----------------

// fm (fp32) -> L0' (fp16) + L1 (fp16). Thread per (L1 texel, quad q); grid (1024, 3).
__global__ __launch_bounds__(256) void mip_convert_l1(
    const float* __restrict__ fm, __half* __restrict__ wsh)
{
    int t = blockIdx.x * 256 + threadIdx.x;
    const int p = blockIdx.y;
    const int q = t & 3, idx = t >> 2;
    const int y = idx >> 8, x = idx & 255;
    const float* sp = fm + (size_t)p * FM_PLANE_STRIDE
                         + ((size_t)(2 * y) * 512 + 2 * x) * 16 + q * 4;
    f4v a = ld4nt(sp);
    f4v b = ld4nt(sp + 16);
    f4v c = ld4nt(sp + 512 * 16);
    f4v d = ld4nt(sp + 512 * 16 + 16);
    __half* L0 = wsh + (size_t)p * PSTRIDE_H;
    size_t o00 = ((size_t)(2 * y) * 512 + 2 * x) * 16 + q * 4;
    *reinterpret_cast<u32x2*>(L0 + o00)                 = pack4(a);
    *reinterpret_cast<u32x2*>(L0 + o00 + 16)            = pack4(b);
    *reinterpret_cast<u32x2*>(L0 + o00 + 512 * 16)      = pack4(c);
    *reinterpret_cast<u32x2*>(L0 + o00 + 512 * 16 + 16) = pack4(d);
    f4v m = (a + b + c + d) * 0.25f;   // L1 from fp32 source, single rounding
    __half* L1 = wsh + (size_t)p * PSTRIDE_H + (size_t)262144 * 16;
    *reinterpret_cast<u32x2*>(L1 + ((size_t)y * 256 + x) * 16 + q * 4) = pack4(m);
}

// Fused L2..L7 (fp16). Block = (32x32 L2 tile, quad q, plane p); grid (16,4,3).
__global__ __launch_bounds__(256) void mip_tail_h(__half* __restrict__ wsh)
{
    const int tile = blockIdx.x;
    const int q    = blockIdx.y;
    const int p    = blockIdx.z;
    const int ty = tile >> 2, tx = tile & 3;
    const int tid = threadIdx.x;

    __shared__ f4v A[32 * 32];
    __shared__ f4v B[16 * 16];

    __half* plane = wsh + (size_t)p * PSTRIDE_H;
    const __half* L1 = plane + (size_t)lvl_off(1) * 16;
    __half* L2 = plane + (size_t)lvl_off(2) * 16;
    __half* L3 = plane + (size_t)lvl_off(3) * 16;
    __half* L4 = plane + (size_t)lvl_off(4) * 16;
    __half* L5 = plane + (size_t)lvl_off(5) * 16;
    __half* L6 = plane + (size_t)lvl_off(6) * 16;
    __half* L7 = plane + (size_t)lvl_off(7) * 16;

    #pragma unroll
    for (int k = 0; k < 4; ++k) {
        int li = tid + k * 256;
        int ly = li >> 5, lx = li & 31;
        int gy = ty * 32 + ly, gx = tx * 32 + lx;
        const __half* sp = L1 + ((size_t)(2 * gy) * 256 + 2 * gx) * 16 + q * 4;
        f4v r = (h4f(sp) + h4f(sp + 16) + h4f(sp + 256 * 16) + h4f(sp + 256 * 16 + 16)) * 0.25f;
        A[li] = r;
        *reinterpret_cast<u32x2*>(L2 + ((size_t)gy * 128 + gx) * 16 + q * 4) = pack4(r);
    }
    __syncthreads();

    {   // L3: 16x16
        int ly = tid >> 4, lx = tid & 15;
        f4v r = (A[(2 * ly) * 32 + 2 * lx]     + A[(2 * ly) * 32 + 2 * lx + 1] +
                 A[(2 * ly + 1) * 32 + 2 * lx] + A[(2 * ly + 1) * 32 + 2 * lx + 1]) * 0.25f;
        B[tid] = r;
        *reinterpret_cast<u32x2*>(L3 + ((size_t)(ty * 16 + ly) * 64 + tx * 16 + lx) * 16 + q * 4) = pack4(r);
    }
    __syncthreads();

    if (tid < 64) {   // L4: 8x8
        int ly = tid >> 3, lx = tid & 7;
        f4v r = (B[(2 * ly) * 16 + 2 * lx]     + B[(2 * ly) * 16 + 2 * lx + 1] +
                 B[(2 * ly + 1) * 16 + 2 * lx] + B[(2 * ly + 1) * 16 + 2 * lx + 1]) * 0.25f;
        A[tid] = r;
        *reinterpret_cast<u32x2*>(L4 + ((size_t)(ty * 8 + ly) * 32 + tx * 8 + lx) * 16 + q * 4) = pack4(r);
    }
    __syncthreads();

    if (tid < 16) {   // L5: 4x4
        int ly = tid >> 2, lx = tid & 3;
        f4v r = (A[(2 * ly) * 8 + 2 * lx]     + A[(2 * ly) * 8 + 2 * lx + 1] +
                 A[(2 * ly + 1) * 8 + 2 * lx] + A[(2 * ly + 1) * 8 + 2 * lx + 1]) * 0.25f;
        B[tid] = r;
        *reinterpret_cast<u32x2*>(L5 + ((size_t)(ty * 4 + ly) * 16 + tx * 4 + lx) * 16 + q * 4) = pack4(r);
    }
    __syncthreads();

    if (tid < 4) {    // L6: 2x2
        int ly = tid >> 1, lx = tid & 1;
        f4v r = (B[(2 * ly) * 4 + 2 * lx]     + B[(2 * ly) * 4 + 2 * lx + 1] +
                 B[(2 * ly + 1) * 4 + 2 * lx] + B[(2 * ly + 1) * 4 + 2 * lx + 1]) * 0.25f;
        A[tid] = r;
        *reinterpret_cast<u32x2*>(L6 + ((size_t)(ty * 2 + ly) * 8 + tx * 2 + lx) * 16 + q * 4) = pack4(r);
    }
    __syncthreads();

    if (tid == 0) {   // L7: 1 texel
        f4v r = (A[0] + A[1] + A[2] + A[3]) * 0.25f;
        *reinterpret_cast<u32x2*>(L7 + ((size_t)ty * 4 + tx) * 16 + q * 4) = pack4(r);
    }
}

// Weighted 8-channel bilinear tap; levels >= 5 read from LDS copy.
__device__ __forceinline__ void bilerp8(
    const __half* __restrict__ wsh, const __half* __restrict__ lds_h,
    int p, int l, float u, float v, int h, float* o)
{
    const int sz = 512 >> l;
    const float fsz = (float)sz;
    float px = u * fsz - 0.5f;
    float py = v * fsz - 0.5f;
    float xf = floorf(px), yf = floorf(py);
    float fx = px - xf, fy = py - yf;
    int xi = (int)xf, yi = (int)yf;
    int xa = min(max(xi, 0), sz - 1);
    int xb = min(xi + 1, sz - 1);      // xi >= -1 always
    int ya = min(max(yi, 0), sz - 1);
    int yb = min(yi + 1, sz - 1);
    f4v q00, q01, q10, q11;
    if (l >= 5) {
        const int sel = (l == 6) ? 256 : ((l == 7) ? 320 : 0);
        const __half* base = lds_h + (size_t)(p * 336 + sel) * 16 + h * 8;
        const __half* r0 = base + (ya * sz) * 16;
        const __half* r1 = base + (yb * sz) * 16;
        q00 = ldraw_h(r0 + xa * 16);
        q01 = ldraw_h(r0 + xb * 16);
        q10 = ldraw_h(r1 + xa * 16);
        q11 = ldraw_h(r1 + xb * 16);
    } else {
        const __half* base = wsh + (size_t)p * PSTRIDE_H + (size_t)lvl_off(l) * 16 + h * 8;
        const __half* r0 = base + (size_t)(ya * sz) * 16;
        const __half* r1 = base + (size_t)(yb * sz) * 16;
        q00 = ldraw_h(r0 + (size_t)xa * 16);
        q01 = ldraw_h(r0 + (size_t)xb * 16);
        q10 = ldraw_h(r1 + (size_t)xa * 16);
        q11 = ldraw_h(r1 + (size_t)xb * 16);
    }
    float gx = 1.f - fx, gy = 1.f - fy;
    float w00 = gx * gy, w01 = fx * gy, w10 = gx * fy, w11 = fx * fy;
    #pragma unroll
    for (int i = 0; i < 4; ++i) {
        float2 a = up2(q00[i]), b = up2(q01[i]), c = up2(q10[i]), d = up2(q11[i]);
        o[2 * i]     = a.x * w00 + b.x * w01 + c.x * w10 + d.x * w11;
        o[2 * i + 1] = a.y * w00 + b.y * w01 + c.y * w10 + d.y * w11;
    }
}

// One thread per (point n, plane p, half h): t = (n*3 + p)*2 + h.
// Block 512; LDS holds levels 5..7 of all 3 planes (31.5 KB) + the block's
// point data (xyz+level for <=87 points, cooperatively staged).
__global__ __launch_bounds__(512) void trimip_sample_h(
    const float* __restrict__ xyz, const float* __restrict__ level,
    const __half* __restrict__ wsh, float* __restrict__ out, int N)
{
    __shared__ u32x4 lds[2016];       // 3 planes * 336 texels * 32 B = 32256 B
    __shared__ float p_xyz[264];      // 88 pts * 3
    __shared__ float p_lvl[88];

    for (int uidx = threadIdx.x; uidx < 2016; uidx += 512) {
        int p = uidx / 672;           // 672 16-B units per plane
        int rem = uidx - p * 672;
        lds[uidx] = *reinterpret_cast<const u32x4*>(
            wsh + (size_t)p * PSTRIDE_H + (size_t)LVL5_OFF * 16 + (size_t)rem * 8);
    }

    // Stage this block's points: t range [b*512, b*512+511] -> n in [n0, n1].
    const int t0 = blockIdx.x * 512;
    const int n0 = t0 / 6;
    int n1 = (t0 + 511) / 6;
    if (n1 > N - 1) n1 = N - 1;
    const int cnt = n1 - n0 + 1;      // <= 87
    {
        int i = threadIdx.x;          // cnt*3 <= 261 < 512: single pass
        if (i < cnt * 3) p_xyz[i] = xyz[n0 * 3 + i];
        int j = i - 384;              // threads 384.. stage level (<=87 < 128)
        if (j >= 0 && j < cnt) p_lvl[j] = level[n0 + j];
    }
    __syncthreads();
    const __half* lds_h = reinterpret_cast<const __half*>(lds);

    int t = t0 + threadIdx.x;
    if (t >= N * 6) return;
    const int h = t & 1;
    const int r = t >> 1;
    const int n = r / 3;
    const int p = r - n * 3;
    const int rn = n - n0;

    const float c0 = p_xyz[rn * 3 + 0];
    const float c1 = p_xyz[rn * 3 + 1];
    const float c2 = p_xyz[rn * 3 + 2];
    const float u = (p == 0) ? c1 : c0;
    const float v = (p == 2) ? c1 : c2;

    float lv = p_lvl[rn];
    lv = fminf(fmaxf(lv, 0.f), 7.f);
    float lf = floorf(lv);
    float f = lv - lf;
    int l0 = (int)lf;
    int l1 = min(l0 + 1, 7);

    float s0[8], s1[8];
    bilerp8(wsh, lds_h, p, l0, u, v, h, s0);
    bilerp8(wsh, lds_h, p, l1, u, v, h, s1);
    float g = 1.f - f;
    f4v oa, ob;
    #pragma unroll
    for (int i = 0; i < 4; ++i) {
        oa[i] = s0[i] * g + s1[i] * f;
        ob[i] = s0[4 + i] * g + s1[4 + i] * f;
    }
    st4nt(out + (size_t)t * 8, oa);
    st4nt(out + (size_t)t * 8 + 4, ob);
}

// ---------------- fp32 fallback path ----------------

__device__ __forceinline__ f4v avg4(f4v a, f4v b, f4v c, f4v d) {
    return (a + b + c + d) * 0.25f;
}

__global__ __launch_bounds__(256) void mip_build_f(
    const float* __restrict__ src, float* __restrict__ dst)
{
    int t = blockIdx.x * blockDim.x + threadIdx.x;
    const int p = blockIdx.y;
    const int q = t & 3, idx = t >> 2;
    const int y = idx >> 8, x = idx & 255;
    const float* sp = src + (size_t)p * FM_PLANE_STRIDE
                          + ((size_t)(2 * y) * 512 + 2 * x) * 16 + q * 4;
    f4v r = avg4(ld4(sp), ld4(sp + 16), ld4(sp + 512 * 16), ld4(sp + 512 * 16 + 16));
    st4(dst + (size_t)p * WS_PLANE_STRIDE + ((size_t)y * 256 + x) * 16 + q * 4, r);
}

__global__ __launch_bounds__(256) void mip_tail_f(float* __restrict__ mips)
{
    const int tile = blockIdx.x, q = blockIdx.y, p = blockIdx.z;
    const int ty = tile >> 2, tx = tile & 3;
    const int tid = threadIdx.x;
    __shared__ f4v A[32 * 32];
    __shared__ f4v B[16 * 16];
    float* plane = mips + (size_t)p * WS_PLANE_STRIDE;
    const float* L1 = plane;
    float* L2 = plane + (size_t)65536 * 16;
    float* L3 = plane + (size_t)81920 * 16;
    float* L4 = plane + (size_t)86016 * 16;
    float* L5 = plane + (size_t)87040 * 16;
    float* L6 = plane + (size_t)87296 * 16;
    float* L7 = plane + (size_t)87360 * 16;

    #pragma unroll
    for (int k = 0; k < 4; ++k) {
        int li = tid + k * 256;
        int ly = li >> 5, lx = li & 31;
        int gy = ty * 32 + ly, gx = tx * 32 + lx;
        const float* sp = L1 + ((size_t)(2 * gy) * 256 + 2 * gx) * 16 + q * 4;
        f4v r = avg4(ld4(sp), ld4(sp + 16), ld4(sp + 256 * 16), ld4(sp + 256 * 16 + 16));
        A[li] = r;
        st4(L2 + ((size_t)gy * 128 + gx) * 16 + q * 4, r);
    }
    __syncthreads();
    {
        int ly = tid >> 4, lx = tid & 15;
        f4v r = avg4(A[(2 * ly) * 32 + 2 * lx],     A[(2 * ly) * 32 + 2 * lx + 1],
                     A[(2 * ly + 1) * 32 + 2 * lx], A[(2 * ly + 1) * 32 + 2 * lx + 1]);
        B[tid] = r;
        st4(L3 + ((size_t)(ty * 16 + ly) * 64 + tx * 16 + lx) * 16 + q * 4, r);
    }
    __syncthreads();
    if (tid < 64) {
        int ly = tid >> 3, lx = tid & 7;
        f4v r = avg4(B[(2 * ly) * 16 + 2 * lx],     B[(2 * ly) * 16 + 2 * lx + 1],
                     B[(2 * ly + 1) * 16 + 2 * lx], B[(2 * ly + 1) * 16 + 2 * lx + 1]);
        A[tid] = r;
        st4(L4 + ((size_t)(ty * 8 + ly) * 32 + tx * 8 + lx) * 16 + q * 4, r);
    }
    __syncthreads();
    if (tid < 16) {
        int ly = tid >> 2, lx = tid & 3;
        f4v r = avg4(A[(2 * ly) * 8 + 2 * lx],     A[(2 * ly) * 8 + 2 * lx + 1],
                     A[(2 * ly + 1) * 8 + 2 * lx], A[(2 * ly + 1) * 8 + 2 * lx + 1]);
        B[tid] = r;
        st4(L5 + ((size_t)(ty * 4 + ly) * 16 + tx * 4 + lx) * 16 + q * 4, r);
    }
    __syncthreads();
    if (tid < 4) {
        int ly = tid >> 1, lx = tid & 1;
        f4v r = avg4(B[(2 * ly) * 4 + 2 * lx],     B[(2 * ly) * 4 + 2 * lx + 1],
                     B[(2 * ly + 1) * 4 + 2 * lx], B[(2 * ly + 1) * 4 + 2 * lx + 1]);
        A[tid] = r;
        st4(L6 + ((size_t)(ty * 2 + ly) * 8 + tx * 2 + lx) * 16 + q * 4, r);
    }
    __syncthreads();
    if (tid == 0) {
        f4v r = avg4(A[0], A[1], A[2], A[3]);
        st4(L7 + ((size_t)ty * 4 + tx) * 16 + q * 4, r);
    }
}

__device__ __forceinline__ f4v bilerp_f(
    const float* __restrict__ fm, const float* __restrict__ mips,
    int p, int l, float u, float v, int q)
{
    const int sz = 512 >> l;
    const float fsz = (float)sz;
    float px = u * fsz - 0.5f;
    float py = v * fsz - 0.5f;
    float xf = floorf(px), yf = floorf(py);
    float fx = px - xf, fy = py - yf;
    int xi = (int)xf, yi = (int)yf;
    int xa = min(max(xi, 0), sz - 1);
    int xb = min(xi + 1, sz - 1);
    int ya = min(max(yi, 0), sz - 1);
    int yb = min(yi + 1, sz - 1);
    const float* base;
    if (l == 0) {
        base = fm + (size_t)p * FM_PLANE_STRIDE;
    } else {
        unsigned off = (262144u - ((unsigned)(sz * sz) << 2)) / 3u;
        base = mips + (size_t)p * WS_PLANE_STRIDE + (size_t)off * 16;
    }
    const float* r0 = base + (size_t)(ya * sz) * 16 + q * 4;
    const float* r1 = base + (size_t)(yb * sz) * 16 + q * 4;
    f4v f00 = ld4(r0 + xa * 16);
    f4v f01 = ld4(r0 + xb * 16);
    f4v f10 = ld4(r1 + xa * 16);
    f4v f11 = ld4(r1 + xb * 16);
    float gx = 1.f - fx, gy = 1.f - fy;
    return (f00 * gx + f01 * fx) * gy + (f10 * gx + f11 * fx) * fy;
}

__global__ __launch_bounds__(256) void trimip_sample_f(
    const float* __restrict__ xyz, const float* __restrict__ level,
    const float* __restrict__ fm, const float* __restrict__ mips,
    float* __restrict__ out, int N)
{
    int t = blockIdx.x * blockDim.x + threadIdx.x;
    if (t >= N * 12) return;
    const int q = t & 3;
    const int r = t >> 2;
    const int n = r / 3;
    const int p = r - n * 3;
    const float c0 = xyz[n * 3 + 0];
    const float c1 = xyz[n * 3 + 1];
    const float c2 = xyz[n * 3 + 2];
    const float u = (p == 0) ? c1 : c0;
    const float v = (p == 2) ? c1 : c2;
    float lv = level[n];
    lv = fminf(fmaxf(lv, 0.f), 7.f);
    float lf = floorf(lv);
    float f = lv - lf;
    int l0 = (int)lf;
    int l1 = min(l0 + 1, 7);
    f4v s0 = bilerp_f(fm, mips, p, l0, u, v, q);
    f4v s1 = bilerp_f(fm, mips, p, l1, u, v, q);
    f4v o = s0 * (1.f - f) + s1 * f;
    st4nt(out + (size_t)t * 4, o);
}

extern "C" void kernel_launch(void* const* d_in, const int* in_sizes, int n_in,
                              void* d_out, int out_size, void* d_ws, size_t ws_size,
                              hipStream_t stream) {
    const float* xyz   = (const float*)d_in[0];
    const float* level = (const float*)d_in[1];
    const float* fm    = (const float*)d_in[2];
    float* out = (float*)d_out;
    const int N = in_sizes[1];

    if (ws_size >= WS_H_BYTES) {
        __half* wsh = (__half*)d_ws;
        mip_convert_l1<<<dim3(1024, 3), dim3(256), 0, stream>>>(fm, wsh);
        mip_tail_h<<<dim3(16, 4, 3), dim3(256), 0, stream>>>(wsh);
        const int total = N * 6;
        trimip_sample_h<<<(total + 511) / 512, 512, 0, stream>>>(xyz, level, wsh, out, N);
    } else {
        float* mips = (float*)d_ws;
        mip_build_f<<<dim3(1024, 3), dim3(256), 0, stream>>>(fm, mips);
        mip_tail_f<<<dim3(16, 4, 3), dim3(256), 0, stream>>>(mips);
        const int total = N * 12;
        trimip_sample_f<<<(total + 255) / 256, 256, 0, stream>>>(xyz, level, fm, mips, out, N);
    }
}